// Round 16
// baseline (146.967 us; speedup 1.0000x reference)
//
#include <hip/hip_runtime.h>
#include <hip/hip_bf16.h>
#include <math.h>

#define EPS 1e-8f
#define BB 32
#define SS 64
#define HH 200
#define LL 20
#define KP 224    // K padded to 7*32
#define KST 232   // LDS row stride (bf16 elems), 16B-aligned, good bank spread
#define SST 68    // att S-tile LDS row stride (floats)

typedef short bf16x8 __attribute__((ext_vector_type(8)));
typedef float f32x4 __attribute__((ext_vector_type(4)));

__device__ inline float bf2f(short u) {
    union { unsigned int i; float f; } v;
    v.i = ((unsigned int)(unsigned short)u) << 16;
    return v.f;
}

// ws layout (floats): meanv 1638400 | maxv 1638400

// ================================================================ kernel 1: fused att + attvec
// 256 blocks, 512 threads. blk = (sd*BB + b)*2 + sh.
__global__ __launch_bounds__(512) void fused1_kernel(
        const float* __restrict__ conp, const float* __restrict__ conh,
        float* __restrict__ meanv, float* __restrict__ maxv) {
    __shared__ __align__(16) float smem[13440];   // 53.8 KB
    int t = threadIdx.x;

    __hip_bfloat16* AT = (__hip_bfloat16*)smem;            // 32*KST bf16 (3712 fl)
    __hip_bfloat16* BT = (__hip_bfloat16*)(smem + 3712);   // 64*KST bf16 (7424 fl)
    float* S_L  = smem + 3712 + 7424;                      // 32*SST = 2176
    float* nrmA = S_L + 32 * SST;                          // 32
    float* nrmB = nrmA + 32;                               // 64
    float* dsum = nrmB + 64;                               // 32

    int blk = blockIdx.x;
    int sh = blk & 1;
    int sdb = blk >> 1;
    int b = sdb & 31, sd = sdb >> 5;
    int dir = sd & 1, side = sd >> 1;

    if (t < 32) nrmA[t] = 0.f;
    if (t < 64) nrmB[t] = 0.f;
    __syncthreads();

    const float* selfb = side ? conh : conp;
    const float* oppb  = side ? conp : conh;

    for (int e = t; e < 32 * 28; e += 512) {
        int sl = e / 28, ck = e % 28, k = ck * 8;
        __align__(16) __hip_bfloat16 r8[8];
        if (k < HH) {
            const float* xp = selfb + (b * SS + sh * 32 + sl) * (2 * HH) + dir * HH + k;
            float xv[8];
            *(float4*)&xv[0] = *(const float4*)xp; *(float4*)&xv[4] = *(const float4*)(xp + 4);
            float ss = 0.f;
#pragma unroll
            for (int i = 0; i < 8; ++i) { r8[i] = __float2bfloat16(xv[i]); ss = fmaf(xv[i], xv[i], ss); }
            atomicAdd(&nrmA[sl], ss);
        } else {
#pragma unroll
            for (int i = 0; i < 8; ++i) r8[i] = __float2bfloat16(0.f);
        }
        *(bf16x8*)&AT[sl * KST + k] = *(bf16x8*)r8;
    }
    for (int e = t; e < 64 * 28; e += 512) {
        int rw = e / 28, ck = e % 28, k = ck * 8;
        __align__(16) __hip_bfloat16 r8[8];
        if (k < HH) {
            const float* xp = oppb + (b * SS + rw) * (2 * HH) + dir * HH + k;
            float xv[8];
            *(float4*)&xv[0] = *(const float4*)xp; *(float4*)&xv[4] = *(const float4*)(xp + 4);
            float ss = 0.f;
#pragma unroll
            for (int i = 0; i < 8; ++i) { r8[i] = __float2bfloat16(xv[i]); ss = fmaf(xv[i], xv[i], ss); }
            atomicAdd(&nrmB[rw], ss);
        } else {
#pragma unroll
            for (int i = 0; i < 8; ++i) r8[i] = __float2bfloat16(0.f);
        }
        *(bf16x8*)&BT[rw * KST + k] = *(bf16x8*)r8;
    }
    __syncthreads();

    // MFMA: S = A @ B^T (32x64). 8 waves, one 16x16 tile each: rt = w&1, ct = w>>1.
    int wv_ = __builtin_amdgcn_readfirstlane(t >> 6);
    int lane = t & 63;
    int q = lane >> 4, c = lane & 15;
    int rt = wv_ & 1, ct = wv_ >> 1;

    f32x4 acc = (f32x4){0.f, 0.f, 0.f, 0.f};
    for (int ks = 0; ks < 7; ++ks) {
        int kb = ks * 32 + q * 8;
        bf16x8 af  = *(const bf16x8*)&AT[(rt * 16 + c) * KST + kb];
        bf16x8 bf_ = *(const bf16x8*)&BT[(ct * 16 + c) * KST + kb];
        acc = __builtin_amdgcn_mfma_f32_16x16x32_bf16(af, bf_, acc, 0, 0, 0);
    }
    {
        int col = ct * 16 + c;
        float no = sqrtf(nrmB[col]);
#pragma unroll
        for (int r = 0; r < 4; ++r) {
            int row = rt * 16 + q * 4 + r;
            float ns = sqrtf(nrmA[row]);
            S_L[row * SST + col] = acc[r] / fmaxf(ns * no, EPS);
        }
    }
    __syncthreads();

    if (t < 32) {
        float sm = 0.f;
        for (int k = 0; k < 64; ++k) sm += S_L[t * SST + k];
        dsum[t] = fmaxf(sm, EPS);
    }
    __syncthreads();

    for (int e = t; e < 32 * 25; e += 512) {
        int s = e / 25, hc = e % 25, h0 = hc * 8;
        float dsv = dsum[s];
        float ms[8], mx[8];
#pragma unroll
        for (int i = 0; i < 8; ++i) { ms[i] = 0.f; mx[i] = -INFINITY; }
        for (int k = 0; k < 64; ++k) {
            float a = S_L[s * SST + k];
            bf16x8 ov = *(const bf16x8*)&BT[k * KST + h0];
#pragma unroll
            for (int i = 0; i < 8; ++i) {
                float tt = a * bf2f(ov[i]);
                ms[i] += tt;
                mx[i] = fmaxf(mx[i], tt);
            }
        }
        int obase = ((sd * BB + b) * SS + sh * 32 + s) * HH + h0;
#pragma unroll
        for (int i = 0; i < 8; ++i) ms[i] /= dsv;
        *(float4*)&meanv[obase]     = *(float4*)&ms[0];
        *(float4*)&meanv[obase + 4] = *(float4*)&ms[4];
        *(float4*)&maxv[obase]      = *(float4*)&mx[0];
        *(float4*)&maxv[obase + 4]  = *(float4*)&mx[4];
    }
}

// ================================================================ kernel 2: match + pairmfma
// blocks [0,768): mp_match v5; blocks [768,2048): pairwise MFMA (norms from staged tiles).
__global__ __launch_bounds__(256) void fused2_kernel(
        const float* __restrict__ conp, const float* __restrict__ conh,
        const float* __restrict__ meanv, const float* __restrict__ maxv,
        const float* __restrict__ w1, const float* __restrict__ w2,
        const float* __restrict__ w3, const float* __restrict__ w4,
        const float* __restrict__ w5, const float* __restrict__ w6,
        const float* __restrict__ w7, const float* __restrict__ w8,
        float* __restrict__ out) {
    __shared__ __align__(16) float smem[15232];   // 60.9 KB union
    int t = threadIdx.x;

    if (blockIdx.x < 768) {
        // ---------------- mp_match v5 (bf16 MFMA)
        __hip_bfloat16* AT = (__hip_bfloat16*)smem;             // 96*KST bf16 (11136 fl)
        __hip_bfloat16* BT = (__hip_bfloat16*)(smem + 11136);   // 32*KST bf16 (3712 fl)
        int blk = blockIdx.x;
        int sh = blk & 1;
        int r_ = blk >> 1;
        int m = r_ % 3;
        int sdb = r_ / 3;
        int b = sdb & 31, sd = sdb >> 5;
        int dir = sd & 1, side = sd >> 1;

        const float* wsrc = (m == 0) ? (dir ? w2 : w1)
                          : (m == 1) ? (dir ? w6 : w5)
                                     : (dir ? w8 : w7);
        const float* xbase = side ? conh : conp;
        const float* opp   = side ? conp : conh;
        int fidx = dir ? 0 : (SS - 1);
        const float* fvr = opp + (b * SS + fidx) * (2 * HH) + dir * HH;

        for (int e = t; e < 32 * 28; e += 256) {
            int sl = e / 28, ck = e % 28;
            int k = ck * 8;
            int s = sh * 32 + sl;
            __align__(16) __hip_bfloat16 r0[8], r1[8], r2[8];
            if (k < HH) {
                const float* xp = xbase + (b * SS + s) * (2 * HH) + dir * HH + k;
                const float* yp = (m == 0) ? (fvr + k)
                                : ((m == 1 ? meanv : maxv) + ((sd * BB + b) * SS + s) * HH + k);
                float xv[8], yv[8];
                *(float4*)&xv[0] = *(const float4*)xp; *(float4*)&xv[4] = *(const float4*)(xp + 4);
                *(float4*)&yv[0] = *(const float4*)yp; *(float4*)&yv[4] = *(const float4*)(yp + 4);
#pragma unroll
                for (int i = 0; i < 8; ++i) {
                    r0[i] = __float2bfloat16(xv[i] * xv[i]);
                    r1[i] = __float2bfloat16(xv[i] * yv[i]);
                    r2[i] = __float2bfloat16(yv[i] * yv[i]);
                }
            } else {
#pragma unroll
                for (int i = 0; i < 8; ++i) {
                    r0[i] = __float2bfloat16(0.f); r1[i] = __float2bfloat16(0.f); r2[i] = __float2bfloat16(0.f);
                }
            }
            *(bf16x8*)&AT[(0 * 32 + sl) * KST + k] = *(bf16x8*)r0;
            *(bf16x8*)&AT[(1 * 32 + sl) * KST + k] = *(bf16x8*)r1;
            *(bf16x8*)&AT[(2 * 32 + sl) * KST + k] = *(bf16x8*)r2;
        }
        for (int e = t; e < 32 * 28; e += 256) {
            int l = e / 28, ck = e % 28;
            int k = ck * 8;
            __align__(16) __hip_bfloat16 wr[8];
            if (l < LL && k < HH) {
                const float* wp = wsrc + l * HH + k;
                float wv[8];
                *(float4*)&wv[0] = *(const float4*)wp; *(float4*)&wv[4] = *(const float4*)(wp + 4);
#pragma unroll
                for (int i = 0; i < 8; ++i) wr[i] = __float2bfloat16(wv[i] * wv[i]);
            } else {
#pragma unroll
                for (int i = 0; i < 8; ++i) wr[i] = __float2bfloat16(0.f);
            }
            *(bf16x8*)&BT[l * KST + k] = *(bf16x8*)wr;
        }
        __syncthreads();

        int wv_ = __builtin_amdgcn_readfirstlane(t >> 6);
        int lane = t & 63;
        int q = lane >> 4, c = lane & 15;
        int slh = wv_ >> 1, ntile = wv_ & 1;

        f32x4 accA = (f32x4){0.f, 0.f, 0.f, 0.f};
        f32x4 accD = (f32x4){0.f, 0.f, 0.f, 0.f};
        f32x4 accB = (f32x4){0.f, 0.f, 0.f, 0.f};
        for (int ks = 0; ks < 7; ++ks) {
            int kb = ks * 32 + q * 8;
            bf16x8 bf = *(const bf16x8*)&BT[(ntile * 16 + c) * KST + kb];
            bf16x8 a0 = *(const bf16x8*)&AT[(0 * 32 + slh * 16 + c) * KST + kb];
            bf16x8 a1 = *(const bf16x8*)&AT[(1 * 32 + slh * 16 + c) * KST + kb];
            bf16x8 a2 = *(const bf16x8*)&AT[(2 * 32 + slh * 16 + c) * KST + kb];
            accA = __builtin_amdgcn_mfma_f32_16x16x32_bf16(a0, bf, accA, 0, 0, 0);
            accD = __builtin_amdgcn_mfma_f32_16x16x32_bf16(a1, bf, accD, 0, 0, 0);
            accB = __builtin_amdgcn_mfma_f32_16x16x32_bf16(a2, bf, accB, 0, 0, 0);
        }

        int l = ntile * 16 + c;
        if (l < LL) {
            int chunk = (m == 0) ? 0 : (m == 1) ? 40 : 60;
#pragma unroll
            for (int r = 0; r < 4; ++r) {
                int s = sh * 32 + slh * 16 + q * 4 + r;
                float cosv = accD[r] / fmaxf(sqrtf(accA[r] * accB[r]), EPS);
                out[side * (BB * SS * 160) + (b * SS + s) * 160 + dir * 80 + chunk + l] = cosv;
            }
        }
    } else {
        // ---------------- pairwise bf16 MFMA (norms from staged tiles)
        __hip_bfloat16* AT = (__hip_bfloat16*)smem;            // 64*KST bf16 (7424 fl)
        __hip_bfloat16* BT = (__hip_bfloat16*)(smem + 7424);   // 64*KST bf16 (7424 fl)
        float* cmL  = smem + 14848;                            // 256 fl
        float* rssA = smem + 15104;                            // 64 fl
        float* rssB = smem + 15168;                            // 64 fl
        int blk = blockIdx.x - 768;
        int l = blk % LL; int db = blk / LL; int b = db & 31; int dir = db >> 5;

        if (t < 64) { rssA[t] = 0.f; rssB[t] = 0.f; }
        __syncthreads();

        const float* wrow = (dir ? w4 : w3) + l * HH;
        const float* Ag = conp + dir * HH;
        const float* Bg = conh + dir * HH;

        for (int e = t; e < 64 * 28; e += 256) {
            int m = e / 28, ck = e - m * 28;
            int k = ck * 8;
            __align__(16) __hip_bfloat16 at8[8];
            __align__(16) __hip_bfloat16 bt8[8];
            if (k < HH) {
                const float* ap = Ag + (b * SS + m) * (2 * HH) + k;
                const float* bp = Bg + (b * SS + m) * (2 * HH) + k;
                const float* wp = wrow + k;
                float4 a0 = *(const float4*)ap, a1 = *(const float4*)(ap + 4);
                float4 b0 = *(const float4*)bp, b1 = *(const float4*)(bp + 4);
                float4 w0 = *(const float4*)wp, w1 = *(const float4*)(wp + 4);
                float av[8] = {a0.x * w0.x, a0.y * w0.y, a0.z * w0.z, a0.w * w0.w,
                               a1.x * w1.x, a1.y * w1.y, a1.z * w1.z, a1.w * w1.w};
                float bv[8] = {b0.x * w0.x, b0.y * w0.y, b0.z * w0.z, b0.w * w0.w,
                               b1.x * w1.x, b1.y * w1.y, b1.z * w1.z, b1.w * w1.w};
                float sa = 0.f, sb = 0.f;
#pragma unroll
                for (int i = 0; i < 8; ++i) {
                    at8[i] = __float2bfloat16(av[i]);
                    bt8[i] = __float2bfloat16(bv[i]);
                    float afv = bf2f(__bfloat16_as_short(at8[i]));
                    float bfv = bf2f(__bfloat16_as_short(bt8[i]));
                    sa = fmaf(afv, afv, sa);
                    sb = fmaf(bfv, bfv, sb);
                }
                atomicAdd(&rssA[m], sa);
                atomicAdd(&rssB[m], sb);
            } else {
#pragma unroll
                for (int ii = 0; ii < 8; ++ii) { at8[ii] = __float2bfloat16(0.f); bt8[ii] = __float2bfloat16(0.f); }
            }
            *(bf16x8*)&AT[m * KST + k] = *(bf16x8*)at8;
            *(bf16x8*)&BT[m * KST + k] = *(bf16x8*)bt8;
        }
        __syncthreads();

        int wv_ = __builtin_amdgcn_readfirstlane(t >> 6);
        int lane = t & 63;
        int q = lane >> 4, c = lane & 15;
        int m0 = wv_ * 16;

        f32x4 acc[4];
#pragma unroll
        for (int ct = 0; ct < 4; ++ct) acc[ct] = (f32x4){0.f, 0.f, 0.f, 0.f};

        for (int ks = 0; ks < 7; ++ks) {
            int kb = ks * 32 + q * 8;
            bf16x8 af = *(const bf16x8*)&AT[(m0 + c) * KST + kb];
#pragma unroll
            for (int ct = 0; ct < 4; ++ct) {
                bf16x8 bf_ = *(const bf16x8*)&BT[(ct * 16 + c) * KST + kb];
                acc[ct] = __builtin_amdgcn_mfma_f32_16x16x32_bf16(af, bf_, acc[ct], 0, 0, 0);
            }
        }

        float na[4], nb[4];
#pragma unroll
        for (int r = 0; r < 4; ++r) na[r] = sqrtf(rssA[m0 + q * 4 + r]);
#pragma unroll
        for (int ct = 0; ct < 4; ++ct) nb[ct] = sqrtf(rssB[ct * 16 + c]);

        float rowm[4] = {-INFINITY, -INFINITY, -INFINITY, -INFINITY};
        float colm[4] = {-INFINITY, -INFINITY, -INFINITY, -INFINITY};
#pragma unroll
        for (int ct = 0; ct < 4; ++ct) {
#pragma unroll
            for (int r = 0; r < 4; ++r) {
                float cv = acc[ct][r] / fmaxf(na[r] * nb[ct], EPS);
                rowm[r] = fmaxf(rowm[r], cv);
                colm[ct] = fmaxf(colm[ct], cv);
            }
        }

#pragma unroll
        for (int r = 0; r < 4; ++r) {
            float v = rowm[r];
            v = fmaxf(v, __shfl_xor(v, 1, 64));
            v = fmaxf(v, __shfl_xor(v, 2, 64));
            v = fmaxf(v, __shfl_xor(v, 4, 64));
            v = fmaxf(v, __shfl_xor(v, 8, 64));
            rowm[r] = v;
        }
        if (c == 0) {
#pragma unroll
            for (int r = 0; r < 4; ++r) {
                int i = m0 + q * 4 + r;
                out[(b * SS + i) * 160 + dir * 80 + 20 + l] = rowm[r];
            }
        }

#pragma unroll
        for (int ct = 0; ct < 4; ++ct) {
            float v = colm[ct];
            v = fmaxf(v, __shfl_xor(v, 16, 64));
            v = fmaxf(v, __shfl_xor(v, 32, 64));
            colm[ct] = v;
        }
        if (q == 0) {
#pragma unroll
            for (int ct = 0; ct < 4; ++ct) cmL[wv_ * 64 + ct * 16 + c] = colm[ct];
        }
        __syncthreads();
        if (t < 64) {
            float m = fmaxf(fmaxf(cmL[t], cmL[64 + t]), fmaxf(cmL[128 + t], cmL[192 + t]));
            out[BB * SS * 160 + (b * SS + t) * 160 + dir * 80 + 20 + l] = m;
        }
    }
}

extern "C" void kernel_launch(void* const* d_in, const int* in_sizes, int n_in,
                              void* d_out, int out_size, void* d_ws, size_t ws_size,
                              hipStream_t stream) {
    const float* conp = (const float*)d_in[0];
    const float* conh = (const float*)d_in[1];
    const float* w1 = (const float*)d_in[2];
    const float* w2 = (const float*)d_in[3];
    const float* w3 = (const float*)d_in[4];
    const float* w4 = (const float*)d_in[5];
    const float* w5 = (const float*)d_in[6];
    const float* w6 = (const float*)d_in[7];
    const float* w7 = (const float*)d_in[8];
    const float* w8 = (const float*)d_in[9];
    float* out = (float*)d_out;
    float* ws  = (float*)d_ws;

    float* meanv  = ws;                        // 1638400
    float* maxv   = meanv + 4 * BB * SS * HH;  // 1638400

    fused1_kernel<<<256, 512, 0, stream>>>(conp, conh, meanv, maxv);
    fused2_kernel<<<2048, 256, 0, stream>>>(conp, conh, meanv, maxv,
                                            w1, w2, w3, w4, w5, w6, w7, w8, out);
}

// Round 18
// 123.971 us; speedup vs baseline: 1.1855x; 1.1855x over previous
//
#include <hip/hip_runtime.h>
#include <hip/hip_bf16.h>
#include <math.h>

#define EPS 1e-8f
#define BB 32
#define SS 64
#define HH 200
#define LL 20
#define KP 224    // K padded to 7*32
#define KST 232   // LDS row stride (bf16 elems), 16B-aligned, good bank spread
#define MST 204   // prep LDS row stride (floats)
#define SST 68    // att S-tile LDS row stride (floats)

typedef short bf16x8 __attribute__((ext_vector_type(8)));
typedef float f32x4 __attribute__((ext_vector_type(4)));

__device__ inline float bf2f(short u) {
    union { unsigned int i; float f; } v;
    v.i = ((unsigned int)(unsigned short)u) << 16;
    return v.f;
}

// ws layout (floats): wn 163840 | meanv 1638400 | maxv 1638400

// ================================================================ kernel 1: prep + attfused
// blocks [0,256): wn (prep); blocks [256,512): fused att+attvec. 512 threads.
__global__ __launch_bounds__(512) void fused1_kernel(
        const float* __restrict__ conp, const float* __restrict__ conh,
        const float* __restrict__ w3, const float* __restrict__ w4,
        float* __restrict__ wn, float* __restrict__ meanv, float* __restrict__ maxv) {
    __shared__ __align__(16) float smem[13440];   // 53.8 KB union
    int t = threadIdx.x;

    if (blockIdx.x < 256) {
        // ---------------- prep: pairwise weighted norms wn
        float* w2L = smem;          // LL*MST = 4080
        float* x2L = smem + 4080;   // 32*MST = 6528
        int wnb = blockIdx.x;
        int sh = wnb & 1, sdb = wnb >> 1;
        int b = sdb & 31, sd = sdb >> 5;
        int dir = sd & 1, side = sd >> 1;
        const float* wsrc = dir ? w4 : w3;
        for (int e = t; e < LL * 25; e += 512) {
            int l = e / 25, c = e % 25, h0 = c * 8;
            float4 u0 = *(const float4*)(wsrc + l * HH + h0);
            float4 u1 = *(const float4*)(wsrc + l * HH + h0 + 4);
            *(float4*)&w2L[l * MST + h0]     = make_float4(u0.x * u0.x, u0.y * u0.y, u0.z * u0.z, u0.w * u0.w);
            *(float4*)&w2L[l * MST + h0 + 4] = make_float4(u1.x * u1.x, u1.y * u1.y, u1.z * u1.z, u1.w * u1.w);
        }
        const float* xbase = side ? conh : conp;
        for (int e = t; e < 32 * 25; e += 512) {
            int s_ = e / 25, c = e % 25, h0 = c * 8;
            const float* xp = xbase + (b * SS + sh * 32 + s_) * (2 * HH) + dir * HH + h0;
            float4 u0 = *(const float4*)xp;
            float4 u1 = *(const float4*)(xp + 4);
            *(float4*)&x2L[s_ * MST + h0]     = make_float4(u0.x * u0.x, u0.y * u0.y, u0.z * u0.z, u0.w * u0.w);
            *(float4*)&x2L[s_ * MST + h0 + 4] = make_float4(u1.x * u1.x, u1.y * u1.y, u1.z * u1.z, u1.w * u1.w);
        }
        __syncthreads();
        for (int o = t; o < 32 * LL; o += 512) {
            int s_ = o / LL, l = o % LL;
            const float4* xp = (const float4*)&x2L[s_ * MST];
            const float4* wp = (const float4*)&w2L[l * MST];
            float a0 = 0.f, a1 = 0.f, a2 = 0.f, a3 = 0.f;
            for (int h4 = 0; h4 < 50; ++h4) {
                float4 x = xp[h4]; float4 w = wp[h4];
                a0 = fmaf(x.x, w.x, a0); a1 = fmaf(x.y, w.y, a1);
                a2 = fmaf(x.z, w.z, a2); a3 = fmaf(x.w, w.w, a3);
            }
            wn[((sd * BB + b) * SS + sh * 32 + s_) * LL + l] = sqrtf(a0 + a1 + a2 + a3);
        }
    } else {
        // ---------------- fused att + attvec
        __hip_bfloat16* AT = (__hip_bfloat16*)smem;            // 32*KST bf16 (3712 fl)
        __hip_bfloat16* BT = (__hip_bfloat16*)(smem + 3712);   // 64*KST bf16 (7424 fl)
        float* S_L  = smem + 3712 + 7424;                      // 32*SST = 2176
        float* nrmA = S_L + 32 * SST;                          // 32
        float* nrmB = nrmA + 32;                               // 64
        float* dsum = nrmB + 64;                               // 32

        int blk = blockIdx.x - 256;
        int sh = blk & 1;
        int sdb = blk >> 1;
        int b = sdb & 31, sd = sdb >> 5;
        int dir = sd & 1, side = sd >> 1;

        if (t < 32) nrmA[t] = 0.f;
        if (t < 64) nrmB[t] = 0.f;
        __syncthreads();

        const float* selfb = side ? conh : conp;
        const float* oppb  = side ? conp : conh;

        for (int e = t; e < 32 * 28; e += 512) {
            int sl = e / 28, ck = e % 28, k = ck * 8;
            __align__(16) __hip_bfloat16 r8[8];
            if (k < HH) {
                const float* xp = selfb + (b * SS + sh * 32 + sl) * (2 * HH) + dir * HH + k;
                float xv[8];
                *(float4*)&xv[0] = *(const float4*)xp; *(float4*)&xv[4] = *(const float4*)(xp + 4);
                float ss = 0.f;
#pragma unroll
                for (int i = 0; i < 8; ++i) { r8[i] = __float2bfloat16(xv[i]); ss = fmaf(xv[i], xv[i], ss); }
                atomicAdd(&nrmA[sl], ss);
            } else {
#pragma unroll
                for (int i = 0; i < 8; ++i) r8[i] = __float2bfloat16(0.f);
            }
            *(bf16x8*)&AT[sl * KST + k] = *(bf16x8*)r8;
        }
        for (int e = t; e < 64 * 28; e += 512) {
            int rw = e / 28, ck = e % 28, k = ck * 8;
            __align__(16) __hip_bfloat16 r8[8];
            if (k < HH) {
                const float* xp = oppb + (b * SS + rw) * (2 * HH) + dir * HH + k;
                float xv[8];
                *(float4*)&xv[0] = *(const float4*)xp; *(float4*)&xv[4] = *(const float4*)(xp + 4);
                float ss = 0.f;
#pragma unroll
                for (int i = 0; i < 8; ++i) { r8[i] = __float2bfloat16(xv[i]); ss = fmaf(xv[i], xv[i], ss); }
                atomicAdd(&nrmB[rw], ss);
            } else {
#pragma unroll
                for (int i = 0; i < 8; ++i) r8[i] = __float2bfloat16(0.f);
            }
            *(bf16x8*)&BT[rw * KST + k] = *(bf16x8*)r8;
        }
        __syncthreads();

        // MFMA: S = A @ B^T (32x64). 8 waves, one 16x16 tile each: rt = w&1, ct = w>>1.
        int wv_ = __builtin_amdgcn_readfirstlane(t >> 6);
        int lane = t & 63;
        int q = lane >> 4, c = lane & 15;
        int rt = wv_ & 1, ct = wv_ >> 1;

        f32x4 acc = (f32x4){0.f, 0.f, 0.f, 0.f};
        for (int ks = 0; ks < 7; ++ks) {
            int kb = ks * 32 + q * 8;
            bf16x8 af  = *(const bf16x8*)&AT[(rt * 16 + c) * KST + kb];
            bf16x8 bf_ = *(const bf16x8*)&BT[(ct * 16 + c) * KST + kb];
            acc = __builtin_amdgcn_mfma_f32_16x16x32_bf16(af, bf_, acc, 0, 0, 0);
        }
        {
            int col = ct * 16 + c;
            float no = sqrtf(nrmB[col]);
#pragma unroll
            for (int r = 0; r < 4; ++r) {
                int row = rt * 16 + q * 4 + r;
                float ns = sqrtf(nrmA[row]);
                S_L[row * SST + col] = acc[r] / fmaxf(ns * no, EPS);
            }
        }
        __syncthreads();

        if (t < 32) {
            float sm = 0.f;
            for (int k = 0; k < 64; ++k) sm += S_L[t * SST + k];
            dsum[t] = fmaxf(sm, EPS);
        }
        __syncthreads();

        for (int e = t; e < 32 * 25; e += 512) {
            int s = e / 25, hc = e % 25, h0 = hc * 8;
            float dsv = dsum[s];
            float ms[8], mx[8];
#pragma unroll
            for (int i = 0; i < 8; ++i) { ms[i] = 0.f; mx[i] = -INFINITY; }
            for (int k = 0; k < 64; ++k) {
                float a = S_L[s * SST + k];
                bf16x8 ov = *(const bf16x8*)&BT[k * KST + h0];
#pragma unroll
                for (int i = 0; i < 8; ++i) {
                    float tt = a * bf2f(ov[i]);
                    ms[i] += tt;
                    mx[i] = fmaxf(mx[i], tt);
                }
            }
            int obase = ((sd * BB + b) * SS + sh * 32 + s) * HH + h0;
#pragma unroll
            for (int i = 0; i < 8; ++i) ms[i] /= dsv;
            *(float4*)&meanv[obase]     = *(float4*)&ms[0];
            *(float4*)&meanv[obase + 4] = *(float4*)&ms[4];
            *(float4*)&maxv[obase]      = *(float4*)&mx[0];
            *(float4*)&maxv[obase + 4]  = *(float4*)&mx[4];
        }
    }
}

// ================================================================ kernel 2: match + pairmfma
// blocks [0,768): mp_match v5; blocks [768,2048): pairwise MFMA. 256 threads.
__global__ __launch_bounds__(256) void fused2_kernel(
        const float* __restrict__ conp, const float* __restrict__ conh,
        const float* __restrict__ meanv, const float* __restrict__ maxv,
        const float* __restrict__ w1, const float* __restrict__ w2,
        const float* __restrict__ w3, const float* __restrict__ w4,
        const float* __restrict__ w5, const float* __restrict__ w6,
        const float* __restrict__ w7, const float* __restrict__ w8,
        const float* __restrict__ wn, float* __restrict__ out) {
    __shared__ __align__(16) float smem[15104];   // 59 KB union
    int t = threadIdx.x;

    if (blockIdx.x < 768) {
        // ---------------- mp_match v5 (bf16 MFMA)
        __hip_bfloat16* AT = (__hip_bfloat16*)smem;             // 96*KST bf16 (11136 fl)
        __hip_bfloat16* BT = (__hip_bfloat16*)(smem + 11136);   // 32*KST bf16 (3712 fl)
        int blk = blockIdx.x;
        int sh = blk & 1;
        int r_ = blk >> 1;
        int m = r_ % 3;
        int sdb = r_ / 3;
        int b = sdb & 31, sd = sdb >> 5;
        int dir = sd & 1, side = sd >> 1;

        const float* wsrc = (m == 0) ? (dir ? w2 : w1)
                          : (m == 1) ? (dir ? w6 : w5)
                                     : (dir ? w8 : w7);
        const float* xbase = side ? conh : conp;
        const float* opp   = side ? conp : conh;
        int fidx = dir ? 0 : (SS - 1);
        const float* fvr = opp + (b * SS + fidx) * (2 * HH) + dir * HH;

        for (int e = t; e < 32 * 28; e += 256) {
            int sl = e / 28, ck = e % 28;
            int k = ck * 8;
            int s = sh * 32 + sl;
            __align__(16) __hip_bfloat16 r0[8], r1[8], r2[8];
            if (k < HH) {
                const float* xp = xbase + (b * SS + s) * (2 * HH) + dir * HH + k;
                const float* yp = (m == 0) ? (fvr + k)
                                : ((m == 1 ? meanv : maxv) + ((sd * BB + b) * SS + s) * HH + k);
                float xv[8], yv[8];
                *(float4*)&xv[0] = *(const float4*)xp; *(float4*)&xv[4] = *(const float4*)(xp + 4);
                *(float4*)&yv[0] = *(const float4*)yp; *(float4*)&yv[4] = *(const float4*)(yp + 4);
#pragma unroll
                for (int i = 0; i < 8; ++i) {
                    r0[i] = __float2bfloat16(xv[i] * xv[i]);
                    r1[i] = __float2bfloat16(xv[i] * yv[i]);
                    r2[i] = __float2bfloat16(yv[i] * yv[i]);
                }
            } else {
#pragma unroll
                for (int i = 0; i < 8; ++i) {
                    r0[i] = __float2bfloat16(0.f); r1[i] = __float2bfloat16(0.f); r2[i] = __float2bfloat16(0.f);
                }
            }
            *(bf16x8*)&AT[(0 * 32 + sl) * KST + k] = *(bf16x8*)r0;
            *(bf16x8*)&AT[(1 * 32 + sl) * KST + k] = *(bf16x8*)r1;
            *(bf16x8*)&AT[(2 * 32 + sl) * KST + k] = *(bf16x8*)r2;
        }
        for (int e = t; e < 32 * 28; e += 256) {
            int l = e / 28, ck = e % 28;
            int k = ck * 8;
            __align__(16) __hip_bfloat16 wr[8];
            if (l < LL && k < HH) {
                const float* wp = wsrc + l * HH + k;
                float wv[8];
                *(float4*)&wv[0] = *(const float4*)wp; *(float4*)&wv[4] = *(const float4*)(wp + 4);
#pragma unroll
                for (int i = 0; i < 8; ++i) wr[i] = __float2bfloat16(wv[i] * wv[i]);
            } else {
#pragma unroll
                for (int i = 0; i < 8; ++i) wr[i] = __float2bfloat16(0.f);
            }
            *(bf16x8*)&BT[l * KST + k] = *(bf16x8*)wr;
        }
        __syncthreads();

        int wv_ = __builtin_amdgcn_readfirstlane(t >> 6);
        int lane = t & 63;
        int q = lane >> 4, c = lane & 15;
        int slh = wv_ >> 1, ntile = wv_ & 1;

        f32x4 accA = (f32x4){0.f, 0.f, 0.f, 0.f};
        f32x4 accD = (f32x4){0.f, 0.f, 0.f, 0.f};
        f32x4 accB = (f32x4){0.f, 0.f, 0.f, 0.f};
        for (int ks = 0; ks < 7; ++ks) {
            int kb = ks * 32 + q * 8;
            bf16x8 bf = *(const bf16x8*)&BT[(ntile * 16 + c) * KST + kb];
            bf16x8 a0 = *(const bf16x8*)&AT[(0 * 32 + slh * 16 + c) * KST + kb];
            bf16x8 a1 = *(const bf16x8*)&AT[(1 * 32 + slh * 16 + c) * KST + kb];
            bf16x8 a2 = *(const bf16x8*)&AT[(2 * 32 + slh * 16 + c) * KST + kb];
            accA = __builtin_amdgcn_mfma_f32_16x16x32_bf16(a0, bf, accA, 0, 0, 0);
            accD = __builtin_amdgcn_mfma_f32_16x16x32_bf16(a1, bf, accD, 0, 0, 0);
            accB = __builtin_amdgcn_mfma_f32_16x16x32_bf16(a2, bf, accB, 0, 0, 0);
        }

        int l = ntile * 16 + c;
        if (l < LL) {
            int chunk = (m == 0) ? 0 : (m == 1) ? 40 : 60;
#pragma unroll
            for (int r = 0; r < 4; ++r) {
                int s = sh * 32 + slh * 16 + q * 4 + r;
                float cosv = accD[r] / fmaxf(sqrtf(accA[r] * accB[r]), EPS);
                out[side * (BB * SS * 160) + (b * SS + s) * 160 + dir * 80 + chunk + l] = cosv;
            }
        }
    } else {
        // ---------------- pairwise bf16 MFMA
        __hip_bfloat16* AT = (__hip_bfloat16*)smem;            // 64*KST bf16 (7424 fl)
        __hip_bfloat16* BT = (__hip_bfloat16*)(smem + 7424);   // 64*KST bf16 (7424 fl)
        float* cmL = smem + 14848;                             // 256 fl
        int blk = blockIdx.x - 768;
        int l = blk % LL; int db = blk / LL; int b = db & 31; int dir = db >> 5;

        const float* wrow = (dir ? w4 : w3) + l * HH;
        const float* Ag = conp + dir * HH;
        const float* Bg = conh + dir * HH;

        for (int e = t; e < 64 * 28; e += 256) {
            int m = e / 28, ck = e - m * 28;
            int k = ck * 8;
            __align__(16) __hip_bfloat16 at8[8];
            __align__(16) __hip_bfloat16 bt8[8];
            if (k < HH) {
                const float* ap = Ag + (b * SS + m) * (2 * HH) + k;
                const float* bp = Bg + (b * SS + m) * (2 * HH) + k;
                const float* wp = wrow + k;
                float4 a0 = *(const float4*)ap, a1 = *(const float4*)(ap + 4);
                float4 b0 = *(const float4*)bp, b1 = *(const float4*)(bp + 4);
                float4 w0 = *(const float4*)wp, w1 = *(const float4*)(wp + 4);
                at8[0] = __float2bfloat16(a0.x * w0.x); at8[1] = __float2bfloat16(a0.y * w0.y);
                at8[2] = __float2bfloat16(a0.z * w0.z); at8[3] = __float2bfloat16(a0.w * w0.w);
                at8[4] = __float2bfloat16(a1.x * w1.x); at8[5] = __float2bfloat16(a1.y * w1.y);
                at8[6] = __float2bfloat16(a1.z * w1.z); at8[7] = __float2bfloat16(a1.w * w1.w);
                bt8[0] = __float2bfloat16(b0.x * w0.x); bt8[1] = __float2bfloat16(b0.y * w0.y);
                bt8[2] = __float2bfloat16(b0.z * w0.z); bt8[3] = __float2bfloat16(b0.w * w0.w);
                bt8[4] = __float2bfloat16(b1.x * w1.x); bt8[5] = __float2bfloat16(b1.y * w1.y);
                bt8[6] = __float2bfloat16(b1.z * w1.z); bt8[7] = __float2bfloat16(b1.w * w1.w);
            } else {
#pragma unroll
                for (int ii = 0; ii < 8; ++ii) { at8[ii] = __float2bfloat16(0.f); bt8[ii] = __float2bfloat16(0.f); }
            }
            *(bf16x8*)&AT[m * KST + k] = *(bf16x8*)at8;
            *(bf16x8*)&BT[m * KST + k] = *(bf16x8*)bt8;
        }
        __syncthreads();

        int wv_ = __builtin_amdgcn_readfirstlane(t >> 6);
        int lane = t & 63;
        int q = lane >> 4, c = lane & 15;
        int m0 = wv_ * 16;

        f32x4 acc[4];
#pragma unroll
        for (int ct = 0; ct < 4; ++ct) acc[ct] = (f32x4){0.f, 0.f, 0.f, 0.f};

        for (int ks = 0; ks < 7; ++ks) {
            int kb = ks * 32 + q * 8;
            bf16x8 af = *(const bf16x8*)&AT[(m0 + c) * KST + kb];
#pragma unroll
            for (int ct = 0; ct < 4; ++ct) {
                bf16x8 bf_ = *(const bf16x8*)&BT[(ct * 16 + c) * KST + kb];
                acc[ct] = __builtin_amdgcn_mfma_f32_16x16x32_bf16(af, bf_, acc[ct], 0, 0, 0);
            }
        }

        float na[4], nb[4];
#pragma unroll
        for (int r = 0; r < 4; ++r) {
            int i = m0 + q * 4 + r;
            na[r] = wn[(((0 * 2 + dir) * BB + b) * SS + i) * LL + l];
        }
#pragma unroll
        for (int ct = 0; ct < 4; ++ct) {
            int j = ct * 16 + c;
            nb[ct] = wn[(((1 * 2 + dir) * BB + b) * SS + j) * LL + l];
        }

        float rowm[4] = {-INFINITY, -INFINITY, -INFINITY, -INFINITY};
        float colm[4] = {-INFINITY, -INFINITY, -INFINITY, -INFINITY};
#pragma unroll
        for (int ct = 0; ct < 4; ++ct) {
#pragma unroll
            for (int r = 0; r < 4; ++r) {
                float cv = acc[ct][r] / fmaxf(na[r] * nb[ct], EPS);
                rowm[r] = fmaxf(rowm[r], cv);
                colm[ct] = fmaxf(colm[ct], cv);
            }
        }

#pragma unroll
        for (int r = 0; r < 4; ++r) {
            float v = rowm[r];
            v = fmaxf(v, __shfl_xor(v, 1, 64));
            v = fmaxf(v, __shfl_xor(v, 2, 64));
            v = fmaxf(v, __shfl_xor(v, 4, 64));
            v = fmaxf(v, __shfl_xor(v, 8, 64));
            rowm[r] = v;
        }
        if (c == 0) {
#pragma unroll
            for (int r = 0; r < 4; ++r) {
                int i = m0 + q * 4 + r;
                out[(b * SS + i) * 160 + dir * 80 + 20 + l] = rowm[r];
            }
        }

#pragma unroll
        for (int ct = 0; ct < 4; ++ct) {
            float v = colm[ct];
            v = fmaxf(v, __shfl_xor(v, 16, 64));
            v = fmaxf(v, __shfl_xor(v, 32, 64));
            colm[ct] = v;
        }
        if (q == 0) {
#pragma unroll
            for (int ct = 0; ct < 4; ++ct) cmL[wv_ * 64 + ct * 16 + c] = colm[ct];
        }
        __syncthreads();
        if (t < 64) {
            float m = fmaxf(fmaxf(cmL[t], cmL[64 + t]), fmaxf(cmL[128 + t], cmL[192 + t]));
            out[BB * SS * 160 + (b * SS + t) * 160 + dir * 80 + 20 + l] = m;
        }
    }
}

extern "C" void kernel_launch(void* const* d_in, const int* in_sizes, int n_in,
                              void* d_out, int out_size, void* d_ws, size_t ws_size,
                              hipStream_t stream) {
    const float* conp = (const float*)d_in[0];
    const float* conh = (const float*)d_in[1];
    const float* w1 = (const float*)d_in[2];
    const float* w2 = (const float*)d_in[3];
    const float* w3 = (const float*)d_in[4];
    const float* w4 = (const float*)d_in[5];
    const float* w5 = (const float*)d_in[6];
    const float* w6 = (const float*)d_in[7];
    const float* w7 = (const float*)d_in[8];
    const float* w8 = (const float*)d_in[9];
    float* out = (float*)d_out;
    float* ws  = (float*)d_ws;

    float* wn     = ws;                        // 163840
    float* meanv  = wn + 4 * BB * SS * LL;     // 1638400
    float* maxv   = meanv + 4 * BB * SS * HH;  // 1638400

    fused1_kernel<<<512, 512, 0, stream>>>(conp, conh, w3, w4, wn, meanv, maxv);
    fused2_kernel<<<2048, 256, 0, stream>>>(conp, conh, meanv, maxv,
                                            w1, w2, w3, w4, w5, w6, w7, w8, wn, out);
}